// Round 10
// baseline (140.193 us; speedup 1.0000x reference)
//
#include <hip/hip_runtime.h>
#include <hip/hip_bf16.h>
#include <stdint.h>

using bf16x8 = __attribute__((ext_vector_type(8))) __bf16;
using f32x4  = __attribute__((ext_vector_type(4))) float;
using i32x4  = __attribute__((ext_vector_type(4))) int;

#define GBM 128
#define GBN 128
#define GBK 32
#define GTHR 256   // 4 waves, 2x2; wave tile 64x64, acc 4x4
#define PROWS 8

__device__ __forceinline__ void gload_lds16(const void* g, void* l) {
  __builtin_amdgcn_global_load_lds((const __attribute__((address_space(1))) void*)g,
                                   (__attribute__((address_space(3))) void*)l,
                                   16, 0, 0);
}

// ---- pack B (row-streaming): 8 whole rows per block, sequential reads ----
// Tile layout (LDS image, GBK=32): tile t = [128 rows][4 slots], unit (row,sl)
// holds W[row][ (sl^(row&3))*8 + t*32 .. +8 ].
__global__ __launch_bounds__(256)
void pack_rows(const int* __restrict__ qw, const float* __restrict__ scales,
               __bf16* __restrict__ wsB, int K, int NG, int nT) {
  const int tid = threadIdx.x;
  const int rloc = tid >> 5;                 // 0..7
  const int ubase = tid & 31;
  const int n = blockIdx.x * PROWS + rloc;
  const int p = n >> 7;                      // panel
  const int rit = n & 127;                   // row in tile
  const int rb3 = rit & 3;
  const float* srow = scales + (size_t)n * NG;
  const int* qrow = qw + (size_t)n * K;
  __bf16* base = wsB + (size_t)p * nT * (GBN * GBK) + (size_t)rit * GBK;

#pragma unroll
  for (int j = 0; j < 16; ++j) {
    const int cu = ubase + j * 32;           // k-unit 0..511
    const i32x4* src = reinterpret_cast<const i32x4*>(qrow + cu * 8);
    i32x4 q0 = src[0], q1 = src[1];
    const float s = srow[cu >> 4];           // GS=128 => 16 units/group
    const int t  = cu >> 2;                  // 4 units per 32-k tile
    const int sl = (cu & 3) ^ rb3;
    bf16x8 w;
    w[0] = (__bf16)((float)q0[0] * s); w[1] = (__bf16)((float)q0[1] * s);
    w[2] = (__bf16)((float)q0[2] * s); w[3] = (__bf16)((float)q0[3] * s);
    w[4] = (__bf16)((float)q1[0] * s); w[5] = (__bf16)((float)q1[1] * s);
    w[6] = (__bf16)((float)q1[2] * s); w[7] = (__bf16)((float)q1[3] * s);
    *reinterpret_cast<bf16x8*>(base + (size_t)t * (GBN * GBK) + sl * 8) = w;
  }
}

// ---- pack A: x fp32 -> bf16, tile-contiguous [by][t][unit], same swizzle ----
__global__ __launch_bounds__(256)
void xcvt_p(const float* __restrict__ x, __bf16* __restrict__ wsA, int K, int nT) {
  const int U  = blockIdx.x * 256 + threadIdx.x;
  const int uu = U & 511;                    // 512 units per tile
  const int tt = (U >> 9) % nT;
  const int by = (U >> 9) / nT;
  const int row = uu >> 2, slot = uu & 3;
  const int c = slot ^ (row & 3);
  const f32x4* src = reinterpret_cast<const f32x4*>(
      x + (size_t)(by * GBM + row) * K + tt * GBK + c * 8);
  f32x4 a = src[0], b = src[1];
  bf16x8 w;
  w[0] = (__bf16)a[0]; w[1] = (__bf16)a[1]; w[2] = (__bf16)a[2]; w[3] = (__bf16)a[3];
  w[4] = (__bf16)b[0]; w[5] = (__bf16)b[1]; w[6] = (__bf16)b[2]; w[7] = (__bf16)b[3];
  *reinterpret_cast<bf16x8*>(wsA + (size_t)U * 8) = w;
}

// ---- packed-operand GEMM: 4 LDS buffers, 3-deep prefetch ----
__global__ __launch_bounds__(GTHR, 2)
void gemm_packed(const __bf16* __restrict__ wsA, const __bf16* __restrict__ wsB,
                 const float* __restrict__ bias, float* __restrict__ out,
                 int N, int K, int gy) {
  __shared__ __bf16 As[4][GBM * GBK];   // 4 x 8 KiB
  __shared__ __bf16 Bs[4][GBN * GBK];   // 4 x 8 KiB

  const int tid  = threadIdx.x;
  const int lane = tid & 63;
  const int wv   = tid >> 6;
  const int wr   = wv >> 1;
  const int wc   = wv & 1;

  int wgid = blockIdx.x;
  if ((gridDim.x & 7) == 0) {
    const int q = gridDim.x >> 3;
    wgid = (blockIdx.x & 7) * q + (blockIdx.x >> 3);
  }
  const int bx = wgid / gy;
  const int by = wgid % gy;

  const int l15 = lane & 15;
  const int l4  = lane >> 4;
  const int nT  = K / GBK;               // 128

  const __bf16* srcA = wsA + (size_t)by * nT * (GBM * GBK);
  const __bf16* srcB = wsB + (size_t)bx * nT * (GBN * GBK);

  f32x4 acc[4][4];
#pragma unroll
  for (int m = 0; m < 4; ++m)
#pragma unroll
    for (int n = 0; n < 4; ++n) acc[m][n] = (f32x4)0.0f;

  // 4 VMEM per thread per stage (2 A + 2 B), wave-uniform LDS bases
  auto STAGE = [&](int buf, int t) {
    const __bf16* a = srcA + (size_t)t * (GBM * GBK);
    const __bf16* b = srcB + (size_t)t * (GBN * GBK);
#pragma unroll
    for (int i = 0; i < 2; ++i) {
      const int ub = (i * 4 + wv) * 64;   // 0..511 across 4 waves
      gload_lds16(a + (size_t)(ub + lane) * 8, &As[buf][ub * 8]);
      gload_lds16(b + (size_t)(ub + lane) * 8, &Bs[buf][ub * 8]);
    }
  };

  auto MF = [&](const __bf16* A_, const __bf16* B_) {
    bf16x8 af[4], bf_[4];
#pragma unroll
    for (int m = 0; m < 4; ++m) {
      const int row = wr * 64 + m * 16 + l15;
      const int sl = l4 ^ (row & 3);
      af[m] = *reinterpret_cast<const bf16x8*>(&A_[row * GBK + sl * 8]);
    }
#pragma unroll
    for (int n = 0; n < 4; ++n) {
      const int col = wc * 64 + n * 16 + l15;
      const int sl = l4 ^ (col & 3);
      bf_[n] = *reinterpret_cast<const bf16x8*>(&B_[col * GBK + sl * 8]);
    }
#pragma unroll
    for (int m = 0; m < 4; ++m)
#pragma unroll
      for (int n = 0; n < 4; ++n)
        acc[m][n] = __builtin_amdgcn_mfma_f32_16x16x32_bf16(af[m], bf_[n], acc[m][n], 0, 0, 0);
  };

  STAGE(0, 0);
  STAGE(1, 1);
  STAGE(2, 2);                            // 12 VMEM outstanding

  for (int t = 0; t < nT; ++t) {
    if (t + 2 < nT)      { asm volatile("s_waitcnt vmcnt(8)" ::: "memory"); }
    else if (t + 1 < nT) { asm volatile("s_waitcnt vmcnt(4)" ::: "memory"); }
    else                 { asm volatile("s_waitcnt vmcnt(0)" ::: "memory"); }
    __builtin_amdgcn_s_barrier();
    __builtin_amdgcn_sched_barrier(0);
    MF(As[t & 3], Bs[t & 3]);
    __builtin_amdgcn_sched_barrier(0);
    __builtin_amdgcn_s_barrier();         // buf (t&3) free for t+4; (t+3)&3 free since t-1
    if (t + 3 < nT) STAGE((t + 3) & 3, t + 3);
    __builtin_amdgcn_sched_barrier(0);
  }

  const int tileM = by * GBM, tileN = bx * GBN;
#pragma unroll
  for (int n = 0; n < 4; ++n) {
    const int col = tileN + wc * 64 + n * 16 + l15;
    const float bv = bias[col];
#pragma unroll
    for (int m = 0; m < 4; ++m) {
      const int rbase = tileM + wr * 64 + m * 16 + l4 * 4;
#pragma unroll
      for (int r = 0; r < 4; ++r)
        out[(size_t)(rbase + r) * N + col] = acc[m][n][r] + bv;
    }
  }
}

// ======================= last-resort fallback (no ws) =======================
#define FBM 128
#define FBN 128
#define FBK 64
__global__ __launch_bounds__(256)
void gptq_gemm_fb(const float* __restrict__ x, const int* __restrict__ qw,
                  const float* __restrict__ scales, const float* __restrict__ bias,
                  float* __restrict__ out, int M, int N, int K, int NG, int GS) {
  __shared__ __bf16 lds_a[FBM * FBK];
  __shared__ __bf16 lds_b[FBN * FBK];
  const int tid = threadIdx.x, lane = tid & 63, wave = tid >> 6;
  const int wr = wave >> 1, wc = wave & 1;
  const int tileM = blockIdx.y * FBM, tileN = blockIdx.x * FBN;
  const int l15 = lane & 15, l4 = lane >> 4;
  f32x4 acc[4][4];
#pragma unroll
  for (int m = 0; m < 4; ++m)
#pragma unroll
    for (int n = 0; n < 4; ++n) acc[m][n] = (f32x4)0.0f;
  for (int k0 = 0; k0 < K; k0 += FBK) {
    const int g = k0 / GS;
#pragma unroll
    for (int i = 0; i < 4; ++i) {
      int u = i * 256 + tid, row = u >> 3, c8 = u & 7;
      const f32x4* src = reinterpret_cast<const f32x4*>(x + (size_t)(tileM + row) * K + k0 + c8 * 8);
      f32x4 v0 = src[0], v1 = src[1];
      bf16x8 w;
      w[0]=(__bf16)v0[0]; w[1]=(__bf16)v0[1]; w[2]=(__bf16)v0[2]; w[3]=(__bf16)v0[3];
      w[4]=(__bf16)v1[0]; w[5]=(__bf16)v1[1]; w[6]=(__bf16)v1[2]; w[7]=(__bf16)v1[3];
      int slot = c8 ^ (row & 7);
      *reinterpret_cast<bf16x8*>(&lds_a[row * FBK + slot * 8]) = w;
    }
#pragma unroll
    for (int i = 0; i < 4; ++i) {
      int u = i * 256 + tid, row = u >> 3, c8 = u & 7;
      int gn = tileN + row;
      const i32x4* src = reinterpret_cast<const i32x4*>(qw + (size_t)gn * K + k0 + c8 * 8);
      i32x4 q0 = src[0], q1 = src[1];
      float s = scales[gn * NG + g];
      bf16x8 w;
      w[0]=(__bf16)((float)q0[0]*s); w[1]=(__bf16)((float)q0[1]*s);
      w[2]=(__bf16)((float)q0[2]*s); w[3]=(__bf16)((float)q0[3]*s);
      w[4]=(__bf16)((float)q1[0]*s); w[5]=(__bf16)((float)q1[1]*s);
      w[6]=(__bf16)((float)q1[2]*s); w[7]=(__bf16)((float)q1[3]*s);
      int slot = c8 ^ (row & 7);
      *reinterpret_cast<bf16x8*>(&lds_b[row * FBK + slot * 8]) = w;
    }
    __syncthreads();
#pragma unroll
    for (int kk = 0; kk < FBK; kk += 32) {
      bf16x8 af[4], bfr[4];
#pragma unroll
      for (int m = 0; m < 4; ++m) {
        int row = wr * 64 + m * 16 + l15, slot = ((kk >> 3) + l4) ^ (row & 7);
        af[m] = *reinterpret_cast<const bf16x8*>(&lds_a[row * FBK + slot * 8]);
      }
#pragma unroll
      for (int n = 0; n < 4; ++n) {
        int row = wc * 64 + n * 16 + l15, slot = ((kk >> 3) + l4) ^ (row & 7);
        bfr[n] = *reinterpret_cast<const bf16x8*>(&lds_b[row * FBK + slot * 8]);
      }
#pragma unroll
      for (int m = 0; m < 4; ++m)
#pragma unroll
        for (int n = 0; n < 4; ++n)
          acc[m][n] = __builtin_amdgcn_mfma_f32_16x16x32_bf16(af[m], bfr[n], acc[m][n], 0, 0, 0);
    }
    __syncthreads();
  }
#pragma unroll
  for (int n = 0; n < 4; ++n) {
    int coln = tileN + wc * 64 + n * 16 + l15;
    float bv = bias[coln];
#pragma unroll
    for (int m = 0; m < 4; ++m) {
      int rbase = tileM + wr * 64 + m * 16 + l4 * 4;
#pragma unroll
      for (int r = 0; r < 4; ++r)
        out[(size_t)(rbase + r) * N + coln] = acc[m][n][r] + bv;
    }
  }
}

extern "C" void kernel_launch(void* const* d_in, const int* in_sizes, int n_in,
                              void* d_out, int out_size, void* d_ws, size_t ws_size,
                              hipStream_t stream) {
  const float* x      = (const float*)d_in[0];
  const int*   qw     = (const int*)d_in[1];
  const float* scales = (const float*)d_in[2];
  const float* bias   = (const float*)d_in[3];
  float*       out    = (float*)d_out;

  const int OUT = in_sizes[3];            // 11008
  const int IN  = in_sizes[1] / OUT;      // 4096
  const int M   = in_sizes[0] / IN;       // 512
  const int NG  = in_sizes[2] / OUT;      // 32
  const int GS  = IN / NG;                // 128

  const size_t needB = (size_t)OUT * IN * sizeof(__bf16);   // 90.2 MB
  const size_t needA = (size_t)M * IN * sizeof(__bf16);     // 4.2 MB
  const int nT = IN / GBK;                                  // 128

  const bool ok_packed =
      (ws_size >= needB + needA) && (M % GBM == 0) && (OUT % GBN == 0) &&
      (IN % (4 * GBK) == 0) && (GS == 128) && (NG == IN / 128) &&
      (OUT % PROWS == 0) && (nT >= 8);

  if (ok_packed) {
    __bf16* wsB = (__bf16*)d_ws;
    __bf16* wsA = (__bf16*)((char*)d_ws + needB);
    pack_rows<<<OUT / PROWS, 256, 0, stream>>>(qw, scales, wsB, IN, NG, nT);
    const int gy = M / GBM;               // 4
    const int unitsA = gy * nT * 512;
    xcvt_p<<<unitsA / 256, 256, 0, stream>>>(x, wsA, IN, nT);
    const int gx = OUT / GBN;             // 86
    gemm_packed<<<gx * gy, GTHR, 0, stream>>>(wsA, wsB, bias, out, OUT, IN, gy);
  } else {
    dim3 grid(OUT / FBN, M / FBM);
    gptq_gemm_fb<<<grid, 256, 0, stream>>>(x, qw, scales, bias, out, M, OUT, IN, NG, GS);
  }
}